// Round 4
// baseline (8634.377 us; speedup 1.0000x reference)
//
#include <hip/hip_runtime.h>

typedef unsigned short u16;
typedef short s16x8 __attribute__((ext_vector_type(8)));
typedef float f32x4 __attribute__((ext_vector_type(4)));
typedef float f32x4u __attribute__((ext_vector_type(4), aligned(4)));
typedef unsigned short us4 __attribute__((ext_vector_type(4)));   // 8 B

__device__ __forceinline__ float bf2f(u16 v) {
    return __uint_as_float(((unsigned int)v) << 16);
}
__device__ __forceinline__ u16 f2bf(float f) {
    unsigned int u = __float_as_uint(f);
    u = u + 0x7FFFu + ((u >> 16) & 1u);
    return (u16)(u >> 16);
}
__device__ __forceinline__ f32x4 mfma16(s16x8 a, s16x8 b, f32x4 c) {
    return __builtin_amdgcn_mfma_f32_16x16x32_bf16(a, b, c, 0, 0, 0);
}
#define ZERO4 f32x4{0.f, 0.f, 0.f, 0.f}

// ============ prepack: f32 weights -> bf16 MFMA B-fragment layouts ============
__global__ void prepack_kernel(const float* __restrict__ conv_w, const float* __restrict__ Wk,
                               const float* __restrict__ Wv, const float* __restrict__ Wq,
                               const float* __restrict__ W1, const float* __restrict__ W2,
                               u16* __restrict__ Bp, u16* __restrict__ WkvP, u16* __restrict__ WqP,
                               u16* __restrict__ W1T, u16* __restrict__ W2T)
{
    int idx = blockIdx.x * 256 + threadIdx.x;
    if (idx < 294912) {                       // 256 n * 1152 groups
        int n = idx / 1152, g = idx - n * 1152;
        int ic = g / 9, r = g - ic * 9;
        const float* s = conv_w + n * 3456 + ic * 27 + r * 3;
        u16* d = Bp + n * 4608 + g * 4;
        d[0] = f2bf(s[0]); d[1] = f2bf(s[1]); d[2] = f2bf(s[2]); d[3] = 0;
    } else if (idx < 425984) {                // WkvP 512*256
        int i = idx - 294912;
        int n = i >> 8, c = i & 255;
        WkvP[i] = f2bf((n < 256) ? Wk[c * 256 + n] : Wv[c * 256 + (n - 256)]);
    } else if (idx < 491520) {                // WqP 256*256
        int i = idx - 425984;
        int n = i >> 8, c = i & 255;
        WqP[i] = f2bf(Wq[c * 256 + n]);
    } else if (idx < 622592) {                // W1T 512*256
        int i = idx - 491520;
        int h = i >> 8, c = i & 255;
        W1T[i] = f2bf(W1[c * 512 + h]);
    } else if (idx < 753664) {                // W2T 256*512
        int i = idx - 622592;
        int dd = i >> 9, h = i & 511;
        W2T[i] = f2bf(W2[h * 256 + dd]);
    }
}

// ============ fused conv3d(s2)+bias+ReLU+LN_in + k/v GEMM (pipelined) ============
// grid 512 = b(8) * ox(16) * oyb(4); block 256 (4 waves)
__global__ __launch_bounds__(256, 2) void conv_fused(
    const float* __restrict__ x, const u16* __restrict__ Bp, const float* __restrict__ conv_b,
    const float* __restrict__ ln_g, const float* __restrict__ ln_b, const u16* __restrict__ WkvP,
    u16* __restrict__ kbuf, u16* __restrict__ vT)
{
    __shared__ __align__(16) char smem[36352];
    u16* slab   = (u16*)smem;                 // [16 ic][3 ix][9 iy][36 iz] = 31104 B
    u16* tokbf  = (u16*)smem;                 // alias: [64 m][264 c] bf16 = 33792 B
    float* lnred  = (float*)(smem + 33792);   // [4 w][64 m][2] = 2048
    float* lnstat = (float*)(smem + 35840);   // [64 m][2] = 512

    int blk = blockIdx.x;
    int b = blk >> 6, ox = (blk >> 2) & 15, oyb = blk & 3;
    int tid = threadIdx.x, wid = tid >> 6, lane = tid & 63;
    int quad = lane >> 4, l15 = lane & 15;
    int nbase = wid * 64;

    // ---- precompute staging slot offsets (icc=0); xo bit30 = single-col flag, -1 = invalid
    int xo[16], so[16];
    #pragma unroll
    for (int u = 0; u < 16; ++u) {
        int s = tid + u * 256;
        xo[u] = -1; so[u] = 0;
        if (s < 3888) {
            int row = (s * 7282) >> 16;           // s/9
            int c = s - row * 9;
            int icl = (row * 2428) >> 16;         // row/27
            int rr = row - icl * 27;
            int ixl = (rr * 7282) >> 16;          // rr/9
            int iyl = rr - ixl * 9;
            int off = ((b * 128 + icl) * 33 + (2 * ox + ixl)) * 1089
                      + (8 * oyb + iyl) * 33 + c * 4;
            xo[u] = off | ((c == 8) ? (1 << 30) : 0);
            so[u] = row * 36 + c * 4;
        }
    }
    f32x4u tv[16];
    #pragma unroll
    for (int u = 0; u < 16; ++u) tv[u] = f32x4u{0.f, 0.f, 0.f, 0.f};

    // issue loads for icc
    auto stage_load = [&](int icc) {
        int base = icc * 574992;                  // 16 ch * 33 * 1089
        #pragma unroll
        for (int u = 0; u < 16; ++u) {
            if (xo[u] >= 0) {
                int off = (xo[u] & 0x3FFFFFFF) + base;
                if (xo[u] & (1 << 30)) tv[u].x = x[off];
                else                   tv[u] = *(const f32x4u*)(x + off);
            }
        }
    };
    stage_load(0);

    f32x4 acc[4][4];
    #pragma unroll
    for (int i = 0; i < 4; ++i)
        #pragma unroll
        for (int j = 0; j < 4; ++j) acc[i][j] = ZERO4;

    for (int icc = 0; icc < 8; ++icc) {
        __syncthreads();          // waves done reading slab from previous icc
        #pragma unroll
        for (int u = 0; u < 16; ++u) {
            if (xo[u] >= 0) {
                us4 w;
                w.x = f2bf(tv[u].x); w.y = f2bf(tv[u].y);
                w.z = f2bf(tv[u].z); w.w = f2bf(tv[u].w);
                *(us4*)(slab + so[u]) = w;
            }
        }
        __syncthreads();          // slab ready
        if (icc < 7) stage_load(icc + 1);   // loads in flight during compute

        // ---- compute: 18 c8-steps, Bp ping-pong prefetch ----
        s16x8 bp[2][4];
        {
            int k0 = icc * 576;
            #pragma unroll
            for (int fn = 0; fn < 4; ++fn)
                bp[0][fn] = *reinterpret_cast<const s16x8*>(
                    Bp + (nbase + fn * 16 + l15) * 4608 + k0 + quad * 8);
        }
        #pragma unroll 1
        for (int c8 = 0; c8 < 18; ++c8) {
            int cur = c8 & 1;
            if (c8 < 17) {
                int k0 = icc * 576 + (c8 + 1) * 32;
                #pragma unroll
                for (int fn = 0; fn < 4; ++fn)
                    bp[cur ^ 1][fn] = *reinterpret_cast<const s16x8*>(
                        Bp + (nbase + fn * 16 + l15) * 4608 + k0 + quad * 8);
            }
            int base0, base1;
            {
                int g = c8 * 8 + quad * 2;
                int icl = g / 9, r9 = g - icl * 9, kx = r9 / 3, ky = r9 - kx * 3;
                base0 = (icl * 3 + kx) * 324 + ky * 36 + 2 * l15;
                g += 1;
                icl = g / 9; r9 = g - icl * 9; kx = r9 / 3; ky = r9 - kx * 3;
                base1 = (icl * 3 + kx) * 324 + ky * 36 + 2 * l15;
            }
            union { s16x8 v; ushort2 h[4]; } af[4];
            #pragma unroll
            for (int fm = 0; fm < 4; ++fm) {
                const u16* sp0 = slab + base0 + fm * 72;
                const u16* sp1 = slab + base1 + fm * 72;
                af[fm].h[0] = *(const ushort2*)(sp0);
                af[fm].h[1] = *(const ushort2*)(sp0 + 2);
                af[fm].h[2] = *(const ushort2*)(sp1);
                af[fm].h[3] = *(const ushort2*)(sp1 + 2);
            }
            #pragma unroll
            for (int fm = 0; fm < 4; ++fm)
                #pragma unroll
                for (int fn = 0; fn < 4; ++fn)
                    acc[fm][fn] = mfma16(af[fm].v, bp[cur][fn], acc[fm][fn]);
        }
    }
    // ---- bias + relu ----
    #pragma unroll
    for (int fn = 0; fn < 4; ++fn) {
        float bias = conv_b[nbase + fn * 16 + l15];
        #pragma unroll
        for (int fm = 0; fm < 4; ++fm)
            #pragma unroll
            for (int r = 0; r < 4; ++r)
                acc[fm][fn][r] = fmaxf(acc[fm][fn][r] + bias, 0.f);
    }
    // ---- LN_in ----
    #pragma unroll
    for (int fm = 0; fm < 4; ++fm) {
        #pragma unroll
        for (int r = 0; r < 4; ++r) {
            float s = acc[fm][0][r] + acc[fm][1][r] + acc[fm][2][r] + acc[fm][3][r];
            float q2 = acc[fm][0][r] * acc[fm][0][r] + acc[fm][1][r] * acc[fm][1][r]
                     + acc[fm][2][r] * acc[fm][2][r] + acc[fm][3][r] * acc[fm][3][r];
            #pragma unroll
            for (int msk = 1; msk <= 8; msk <<= 1) {
                s  += __shfl_xor(s, msk, 64);
                q2 += __shfl_xor(q2, msk, 64);
            }
            if (l15 == 0) {
                int mm = fm * 16 + quad * 4 + r;
                lnred[(wid * 64 + mm) * 2 + 0] = s;
                lnred[(wid * 64 + mm) * 2 + 1] = q2;
            }
        }
    }
    __syncthreads();
    if (tid < 64) {
        float s = 0, q2 = 0;
        #pragma unroll
        for (int w = 0; w < 4; ++w) { s += lnred[(w * 64 + tid) * 2]; q2 += lnred[(w * 64 + tid) * 2 + 1]; }
        float mu = s * (1.f / 256.f);
        float var = fmaxf(q2 * (1.f / 256.f) - mu * mu, 0.f);
        lnstat[tid * 2]     = mu;
        lnstat[tid * 2 + 1] = rsqrtf(var + 1e-5f);
    }
    __syncthreads();
    {
        float gam[4], bet[4];
        #pragma unroll
        for (int fn = 0; fn < 4; ++fn) {
            int n = nbase + fn * 16 + l15;
            gam[fn] = ln_g[n]; bet[fn] = ln_b[n];
        }
        #pragma unroll
        for (int fm = 0; fm < 4; ++fm)
            #pragma unroll
            for (int r = 0; r < 4; ++r) {
                int mm = fm * 16 + quad * 4 + r;
                float mu = lnstat[mm * 2], rs = lnstat[mm * 2 + 1];
                #pragma unroll
                for (int fn = 0; fn < 4; ++fn) {
                    int n = nbase + fn * 16 + l15;
                    tokbf[mm * 264 + n] = f2bf((acc[fm][fn][r] - mu) * rs * gam[fn] + bet[fn]);
                }
            }
    }
    __syncthreads();
    // ---- k/v GEMM ----
    f32x4 kacc[4][8];
    #pragma unroll
    for (int i = 0; i < 4; ++i)
        #pragma unroll
        for (int j = 0; j < 8; ++j) kacc[i][j] = ZERO4;
    int n2 = wid * 128;
    #pragma unroll 1
    for (int kc = 0; kc < 8; ++kc) {
        s16x8 a2[4];
        #pragma unroll
        for (int fm = 0; fm < 4; ++fm)
            a2[fm] = *reinterpret_cast<const s16x8*>(tokbf + (fm * 16 + l15) * 264 + kc * 32 + quad * 8);
        #pragma unroll
        for (int fn = 0; fn < 8; ++fn) {
            s16x8 bv = *reinterpret_cast<const s16x8*>(WkvP + (n2 + fn * 16 + l15) * 256 + kc * 32 + quad * 8);
            #pragma unroll
            for (int fm = 0; fm < 4; ++fm)
                kacc[fm][fn] = mfma16(a2[fm], bv, kacc[fm][fn]);
        }
    }
    #pragma unroll
    for (int fm = 0; fm < 4; ++fm)
        #pragma unroll
        for (int r = 0; r < 4; ++r) {
            int mm = fm * 16 + quad * 4 + r;
            int l = (ox * 16 + oyb * 4 + (mm >> 4)) * 16 + (mm & 15);
            #pragma unroll
            for (int fn = 0; fn < 8; ++fn) {
                int n = n2 + fn * 16 + l15;
                u16 v = f2bf(kacc[fm][fn][r]);
                if (n < 256) kbuf[((b << 12) + l) * 256 + n] = v;           // k[b][l][d]
                else         vT[((b * 256 + (n - 256)) << 12) + l] = v;     // vT[b][d][l]
            }
        }
}

// ============ kQ: init tpl, zero colsum/delta, LN_t + q (iter 0) ============
__global__ __launch_bounds__(256) void kQ(
    const float* __restrict__ tinit, float* __restrict__ tpl,
    const float* __restrict__ ln_t_g, const float* __restrict__ ln_t_b,
    const u16* __restrict__ WqP, u16* __restrict__ qbuf,
    float* __restrict__ colsum, float* __restrict__ delta)
{
    __shared__ __align__(16) u16 mls[64 * 264];
    __shared__ float pls[64][4][2];
    __shared__ float stat[64][2];
    int b = blockIdx.x, tid = threadIdx.x;
    int m = tid >> 2, part = tid & 3;
    const float* tp = tinit + m * 256 + part * 64;
    float* tg = tpl + (b * 64 + m) * 256 + part * 64;
    float s = 0, q2 = 0;
    for (int i = 0; i < 64; ++i) {
        float v = tp[i];
        tg[i] = v;
        s += v; q2 += v * v;
    }
    pls[m][part][0] = s; pls[m][part][1] = q2;
    __syncthreads();
    if (tid < 64) {
        float ss = 0, qq = 0;
        #pragma unroll
        for (int p = 0; p < 4; ++p) { ss += pls[tid][p][0]; qq += pls[tid][p][1]; }
        float mu = ss * (1.f / 256.f);
        float var = fmaxf(qq * (1.f / 256.f) - mu * mu, 0.f);
        stat[tid][0] = mu; stat[tid][1] = rsqrtf(var + 1e-5f);
    }
    __syncthreads();
    {
        float mu = stat[m][0], rs = stat[m][1];
        for (int i = 0; i < 64; ++i) {
            int d = part * 64 + i;
            mls[m * 264 + d] = f2bf((tp[i] - mu) * rs * ln_t_g[d] + ln_t_b[d]);
        }
    }
    __syncthreads();
    int wid = tid >> 6, lane = tid & 63, quad = lane >> 4, l15 = lane & 15;
    f32x4 qa[4][4];
    #pragma unroll
    for (int i = 0; i < 4; ++i)
        #pragma unroll
        for (int j = 0; j < 4; ++j) qa[i][j] = ZERO4;
    #pragma unroll 1
    for (int kc = 0; kc < 8; ++kc) {
        s16x8 a[4];
        #pragma unroll
        for (int fm = 0; fm < 4; ++fm)
            a[fm] = *reinterpret_cast<const s16x8*>(mls + (fm * 16 + l15) * 264 + kc * 32 + quad * 8);
        #pragma unroll
        for (int fn = 0; fn < 4; ++fn) {
            s16x8 bv = *reinterpret_cast<const s16x8*>(WqP + (wid * 64 + fn * 16 + l15) * 256 + kc * 32 + quad * 8);
            #pragma unroll
            for (int fm = 0; fm < 4; ++fm)
                qa[fm][fn] = mfma16(a[fm], bv, qa[fm][fn]);
        }
    }
    #pragma unroll
    for (int fm = 0; fm < 4; ++fm)
        #pragma unroll
        for (int fn = 0; fn < 4; ++fn)
            #pragma unroll
            for (int r = 0; r < 4; ++r) {
                int mt = fm * 16 + quad * 4 + r;
                int d = wid * 64 + fn * 16 + l15;
                qbuf[(b * 64 + mt) * 256 + d] = f2bf(qa[fm][fn][r] * 0.0625f);
            }
    if (tid < 64) colsum[b * 64 + tid] = 0.f;
    f32x4* dz = (f32x4*)(delta + b * 16384);
    for (int i = tid; i < 4096; i += 256) dz[i] = ZERO4;
}

// ============ kP: logits + softmax(N) + colsum + PV into delta (atomics) ============
// grid 128 = b(8) * ltg(16); block 256; 256 l rows per block
__global__ __launch_bounds__(256) void kP(
    const u16* __restrict__ qbuf, const u16* __restrict__ kbuf, const u16* __restrict__ vT,
    float* __restrict__ colsum, float* __restrict__ delta, int last, u16* __restrict__ attnT)
{
    __shared__ __align__(16) u16 atile[64 * 264];     // [n][l_local] bf16
    int b = blockIdx.x >> 4, ltg = blockIdx.x & 15;
    int tid = threadIdx.x, wid = tid >> 6, lane = tid & 63;
    int quad = lane >> 4, l15 = lane & 15;
    const u16* qb = qbuf + b * 16384;
    float colp[4] = {0.f, 0.f, 0.f, 0.f};
    #pragma unroll 1
    for (int rt = 0; rt < 4; ++rt) {
        int lrow = ltg * 256 + wid * 64 + rt * 16;
        const u16* arow = kbuf + ((b << 12) + lrow + l15) * 256;
        f32x4 sa[4];
        #pragma unroll
        for (int fn = 0; fn < 4; ++fn) sa[fn] = ZERO4;
        #pragma unroll 1
        for (int kc = 0; kc < 8; ++kc) {
            s16x8 a = *reinterpret_cast<const s16x8*>(arow + kc * 32 + quad * 8);
            #pragma unroll
            for (int fn = 0; fn < 4; ++fn) {
                s16x8 bv = *reinterpret_cast<const s16x8*>(qb + (fn * 16 + l15) * 256 + kc * 32 + quad * 8);
                sa[fn] = mfma16(a, bv, sa[fn]);
            }
        }
        #pragma unroll
        for (int r = 0; r < 4; ++r) {
            float mx = fmaxf(fmaxf(sa[0][r], sa[1][r]), fmaxf(sa[2][r], sa[3][r]));
            #pragma unroll
            for (int msk = 1; msk <= 8; msk <<= 1) mx = fmaxf(mx, __shfl_xor(mx, msk, 64));
            float e[4], sum = 0;
            #pragma unroll
            for (int fn = 0; fn < 4; ++fn) { e[fn] = __expf(sa[fn][r] - mx); sum += e[fn]; }
            #pragma unroll
            for (int msk = 1; msk <= 8; msk <<= 1) sum += __shfl_xor(sum, msk, 64);
            float inv = 1.f / sum;
            #pragma unroll
            for (int fn = 0; fn < 4; ++fn) {
                float p = e[fn] * inv + 1e-8f;
                colp[fn] += p;
                atile[(fn * 16 + l15) * 264 + wid * 64 + rt * 16 + quad * 4 + r] = f2bf(p);
            }
        }
    }
    #pragma unroll
    for (int fn = 0; fn < 4; ++fn) {
        float c = colp[fn];
        c += __shfl_xor(c, 16, 64);
        c += __shfl_xor(c, 32, 64);
        if (lane < 16 && fn == (lane >> 2) * 0) {}   // keep structure simple below
        colp[fn] = c;
    }
    if (lane < 16) {
        #pragma unroll
        for (int fn = 0; fn < 4; ++fn)
            atomicAdd(&colsum[b * 64 + fn * 16 + lane], colp[fn]);
    }
    __syncthreads();
    // ---- PV: delta[n][d] += atile[n][l] * vT[d][l], K=256 ----
    f32x4 acc[4][4];
    #pragma unroll
    for (int i = 0; i < 4; ++i)
        #pragma unroll
        for (int j = 0; j < 4; ++j) acc[i][j] = ZERO4;
    #pragma unroll 1
    for (int kc = 0; kc < 8; ++kc) {
        s16x8 a[4];
        #pragma unroll
        for (int fm = 0; fm < 4; ++fm)
            a[fm] = *reinterpret_cast<const s16x8*>(atile + (fm * 16 + l15) * 264 + kc * 32 + quad * 8);
        #pragma unroll
        for (int fn = 0; fn < 4; ++fn) {
            s16x8 bv = *reinterpret_cast<const s16x8*>(
                vT + ((b * 256 + wid * 64 + fn * 16 + l15) << 12) + ltg * 256 + kc * 32 + quad * 8);
            #pragma unroll
            for (int fm = 0; fm < 4; ++fm)
                acc[fm][fn] = mfma16(a[fm], bv, acc[fm][fn]);
        }
    }
    #pragma unroll
    for (int fm = 0; fm < 4; ++fm)
        #pragma unroll
        for (int fn = 0; fn < 4; ++fn)
            #pragma unroll
            for (int r = 0; r < 4; ++r) {
                int nt = fm * 16 + quad * 4 + r;
                int d = wid * 64 + fn * 16 + l15;
                atomicAdd(&delta[(b * 64 + nt) * 256 + d], acc[fm][fn][r]);
            }
    if (last) {
        int n = tid >> 2, lo = (tid & 3) * 64;
        const u16* src = atile + n * 264 + lo;
        u16* dst = attnT + ((b * 64 + n) << 12) + ltg * 256 + lo;
        #pragma unroll
        for (int j = 0; j < 8; ++j)
            *(int4*)(dst + j * 8) = *(const int4*)(src + j * 8);
    }
}

// ============ kT: tpl += delta/colsum; LN_m; MLP; tpl += mlp; LN_t + q (next) ============
// grid 32 = b(8) * mg(4); 16 templates per block
__global__ __launch_bounds__(256) void kT(
    float* __restrict__ tpl, const float* __restrict__ delta, float* __restrict__ colsum,
    const float* __restrict__ ln_m_g, const float* __restrict__ ln_m_b,
    const u16* __restrict__ W1T, const float* __restrict__ b1,
    const u16* __restrict__ W2T, const float* __restrict__ b2,
    const float* __restrict__ ln_t_g, const float* __restrict__ ln_t_b,
    const u16* __restrict__ WqP, u16* __restrict__ qbuf,
    float* __restrict__ deltaz, int last, float* __restrict__ out0)
{
    __shared__ __align__(16) u16 mls[16 * 264];      // 8448
    __shared__ __align__(16) u16 hid[16 * 520];      // 16640
    __shared__ float pls[16][16][2];                 // 2048
    __shared__ float stat[16][2];
    __shared__ float lnr2[4][16][2];
    int b = blockIdx.x >> 2, mg = blockIdx.x & 3;
    int m0 = mg * 16;
    int tid = threadIdx.x, wid = tid >> 6, lane = tid & 63;
    int quad = lane >> 4, l15 = lane & 15;
    // ---- phase 1: v = tpl + delta/colsum; LN_m -> mls; tpl = v ----
    {
        int ml = tid >> 4, part = tid & 15;
        float cinv = 1.f / colsum[b * 64 + m0 + ml];
        float* tg = tpl + (b * 64 + m0 + ml) * 256 + part * 16;
        const float* dg = delta + (b * 64 + m0 + ml) * 256 + part * 16;
        float vbuf[16];
        float s = 0, q2 = 0;
        #pragma unroll
        for (int i = 0; i < 16; ++i) {
            float v = tg[i] + dg[i] * cinv;
            vbuf[i] = v; s += v; q2 += v * v;
        }
        pls[ml][part][0] = s; pls[ml][part][1] = q2;
        __syncthreads();
        if (tid < 16) {
            float ss = 0, qq = 0;
            #pragma unroll
            for (int p = 0; p < 16; ++p) { ss += pls[tid][p][0]; qq += pls[tid][p][1]; }
            float mu = ss * (1.f / 256.f);
            float var = fmaxf(qq * (1.f / 256.f) - mu * mu, 0.f);
            stat[tid][0] = mu; stat[tid][1] = rsqrtf(var + 1e-5f);
        }
        __syncthreads();
        float mu = stat[ml][0], rs = stat[ml][1];
        #pragma unroll
        for (int i = 0; i < 16; ++i) {
            int d = part * 16 + i;
            tg[i] = vbuf[i];
            mls[ml * 264 + d] = f2bf((vbuf[i] - mu) * rs * ln_m_g[d] + ln_m_b[d]);
        }
    }
    __syncthreads();
    // ---- G1: hid = gelu(mls @ W1 + b1); wave -> 128 nh slice ----
    {
        f32x4 ha[8];
        #pragma unroll
        for (int j = 0; j < 8; ++j) ha[j] = ZERO4;
        #pragma unroll 1
        for (int kc = 0; kc < 8; ++kc) {
            s16x8 a = *reinterpret_cast<const s16x8*>(mls + l15 * 264 + kc * 32 + quad * 8);
            #pragma unroll
            for (int fn = 0; fn < 8; ++fn) {
                s16x8 bv = *reinterpret_cast<const s16x8*>(W1T + (wid * 128 + fn * 16 + l15) * 256 + kc * 32 + quad * 8);
                ha[fn] = mfma16(a, bv, ha[fn]);
            }
        }
        #pragma unroll
        for (int fn = 0; fn < 8; ++fn) {
            int nh = wid * 128 + fn * 16 + l15;
            float bb = b1[nh];
            #pragma unroll
            for (int r = 0; r < 4; ++r) {
                float v = ha[fn][r] + bb;
                v = 0.5f * v * (1.f + erff(v * 0.70710678118654752f));
                hid[(quad * 4 + r) * 520 + nh] = f2bf(v);
            }
        }
    }
    __syncthreads();
    // ---- G2: new = tpl + hid @ W2 + b2; LN_t -> mls; out0 on last ----
    {
        f32x4 oa[4];
        #pragma unroll
        for (int j = 0; j < 4; ++j) oa[j] = ZERO4;
        #pragma unroll 1
        for (int kc = 0; kc < 16; ++kc) {
            s16x8 a = *reinterpret_cast<const s16x8*>(hid + l15 * 520 + kc * 32 + quad * 8);
            #pragma unroll
            for (int fn = 0; fn < 4; ++fn) {
                s16x8 bv = *reinterpret_cast<const s16x8*>(W2T + (wid * 64 + fn * 16 + l15) * 512 + kc * 32 + quad * 8);
                oa[fn] = mfma16(a, bv, oa[fn]);
            }
        }
        #pragma unroll
        for (int fn = 0; fn < 4; ++fn) {
            int d = wid * 64 + fn * 16 + l15;
            float bb = b2[d];
            #pragma unroll
            for (int r = 0; r < 4; ++r) {
                int mm = quad * 4 + r;
                oa[fn][r] += bb + tpl[(b * 64 + m0 + mm) * 256 + d];
            }
        }
        // LN_t stats over the 16 new template rows
        #pragma unroll
        for (int r = 0; r < 4; ++r) {
            float s = oa[0][r] + oa[1][r] + oa[2][r] + oa[3][r];
            float q2 = oa[0][r] * oa[0][r] + oa[1][r] * oa[1][r]
                     + oa[2][r] * oa[2][r] + oa[3][r] * oa[3][r];
            #pragma unroll
            for (int msk = 1; msk <= 8; msk <<= 1) {
                s  += __shfl_xor(s, msk, 64);
                q2 += __shfl_xor(q2, msk, 64);
            }
            if (l15 == 0) {
                lnr2[wid][quad * 4 + r][0] = s;
                lnr2[wid][quad * 4 + r][1] = q2;
            }
        }
        __syncthreads();
        if (tid < 16) {
            float ss = 0, qq = 0;
            #pragma unroll
            for (int w = 0; w < 4; ++w) { ss += lnr2[w][tid][0]; qq += lnr2[w][tid][1]; }
            float mu = ss * (1.f / 256.f);
            float var = fmaxf(qq * (1.f / 256.f) - mu * mu, 0.f);
            stat[tid][0] = mu; stat[tid][1] = rsqrtf(var + 1e-5f);
        }
        __syncthreads();
        #pragma unroll
        for (int fn = 0; fn < 4; ++fn) {
            int d = wid * 64 + fn * 16 + l15;
            float gg = last ? 0.f : ln_t_g[d];
            float bt = last ? 0.f : ln_t_b[d];
            #pragma unroll
            for (int r = 0; r < 4; ++r) {
                int mm = quad * 4 + r;
                float v = oa[fn][r];
                tpl[(b * 64 + m0 + mm) * 256 + d] = v;
                if (last) {
                    out0[(b * 256 + d) * 64 + m0 + mm] = v;
                } else {
                    mls[mm * 264 + d] = f2bf((v - stat[mm][0]) * stat[mm][1] * gg + bt);
                }
            }
        }
    }
    if (!last) {
        __syncthreads();
        // ---- q-GEMM for next iteration ----
        f32x4 qa[4];
        #pragma unroll
        for (int j = 0; j < 4; ++j) qa[j] = ZERO4;
        #pragma unroll 1
        for (int kc = 0; kc < 8; ++kc) {
            s16x8 a = *reinterpret_cast<const s16x8*>(mls + l15 * 264 + kc * 32 + quad * 8);
            #pragma unroll
            for (int fn = 0; fn < 4; ++fn) {
                s16x8 bv = *reinterpret_cast<const s16x8*>(WqP + (wid * 64 + fn * 16 + l15) * 256 + kc * 32 + quad * 8);
                qa[fn] = mfma16(a, bv, qa[fn]);
            }
        }
        #pragma unroll
        for (int fn = 0; fn < 4; ++fn)
            #pragma unroll
            for (int r = 0; r < 4; ++r) {
                int mt = m0 + quad * 4 + r;
                int d = wid * 64 + fn * 16 + l15;
                qbuf[(b * 64 + mt) * 256 + d] = f2bf(qa[fn][r] * 0.0625f);
            }
        if (tid < 16) colsum[b * 64 + m0 + tid] = 0.f;
        f32x4* dz = (f32x4*)(deltaz + (b * 64 + m0) * 256);
        for (int i = tid; i < 1024; i += 256) dz[i] = ZERO4;
    }
}

// ============ kE: attn_out = attnT / colsum ============
__global__ void kE(const u16* __restrict__ attnT, const float* __restrict__ colsum,
                   float* __restrict__ out1)
{
    int idx = blockIdx.x * 256 + threadIdx.x;   // < 524288 (x4 elements)
    int e = idx * 4;
    int b = e >> 18, n = (e >> 12) & 63;
    float ci = 1.f / colsum[b * 64 + n];
    const u16* s = attnT + e;
    f32x4 o;
    o.x = bf2f(s[0]) * ci; o.y = bf2f(s[1]) * ci;
    o.z = bf2f(s[2]) * ci; o.w = bf2f(s[3]) * ci;
    *(f32x4*)(out1 + e) = o;
}

// ============ launch ============
extern "C" void kernel_launch(void* const* d_in, const int* in_sizes, int n_in,
                              void* d_out, int out_size, void* d_ws, size_t ws_size,
                              hipStream_t stream)
{
    const float* x       = (const float*)d_in[0];
    const float* tinit   = (const float*)d_in[1];
    const float* conv_w  = (const float*)d_in[2];
    const float* conv_b  = (const float*)d_in[3];
    const float* Wq      = (const float*)d_in[4];
    const float* Wk      = (const float*)d_in[5];
    const float* Wv      = (const float*)d_in[6];
    const float* ln_in_g = (const float*)d_in[7];
    const float* ln_in_b = (const float*)d_in[8];
    const float* ln_t_g  = (const float*)d_in[9];
    const float* ln_t_b  = (const float*)d_in[10];
    const float* ln_m_g  = (const float*)d_in[11];
    const float* ln_m_b  = (const float*)d_in[12];
    const float* W1      = (const float*)d_in[13];
    const float* b1      = (const float*)d_in[14];
    const float* W2      = (const float*)d_in[15];
    const float* b2      = (const float*)d_in[16];

    char* ws = (char*)d_ws;
    u16* Bp       = (u16*)(ws + 0);          // 2,359,296
    u16* WkvP     = (u16*)(ws + 2359296);    //   262,144
    u16* WqP      = (u16*)(ws + 2621440);    //   131,072
    u16* W1T      = (u16*)(ws + 2752512);    //   262,144
    u16* W2T      = (u16*)(ws + 3014656);    //   262,144
    u16* kbuf     = (u16*)(ws + 3276800);    // 16,777,216
    u16* vT       = (u16*)(ws + 20054016);   // 16,777,216
    u16* qbuf     = (u16*)(ws + 36831232);   //   262,144
    u16* attnT    = (u16*)(ws + 37093376);   // 4,194,304
    float* colsum = (float*)(ws + 41287680); //     2,048
    float* tpl    = (float*)(ws + 41289728); //   524,288
    float* delta  = (float*)(ws + 41814016); //   524,288   (total ~42.3 MB)

    float* out0 = (float*)d_out;      // templates_out (8,256,64)
    float* out1 = out0 + 131072;      // attn_out (8,64,16,16,16)

    prepack_kernel<<<2944, 256, 0, stream>>>(conv_w, Wk, Wv, Wq, W1, W2, Bp, WkvP, WqP, W1T, W2T);
    conv_fused<<<512, 256, 0, stream>>>(x, Bp, conv_b, ln_in_g, ln_in_b, WkvP, kbuf, vT);
    kQ<<<8, 256, 0, stream>>>(tinit, tpl, ln_t_g, ln_t_b, WqP, qbuf, colsum, delta);
    for (int it = 0; it < 6; ++it) {
        int last = (it == 5) ? 1 : 0;
        kP<<<128, 256, 0, stream>>>(qbuf, kbuf, vT, colsum, delta, last, attnT);
        kT<<<32, 256, 0, stream>>>(tpl, delta, colsum, ln_m_g, ln_m_b, W1T, b1, W2T, b2,
                                   ln_t_g, ln_t_b, WqP, qbuf, delta, last, out0);
    }
    kE<<<2048, 256, 0, stream>>>(attnT, colsum, out1);
}

// Round 5
// 962.642 us; speedup vs baseline: 8.9695x; 8.9695x over previous
//
#include <hip/hip_runtime.h>

typedef unsigned short u16;
typedef short s16x8 __attribute__((ext_vector_type(8)));
typedef float f32x4 __attribute__((ext_vector_type(4)));
typedef float f32x4u __attribute__((ext_vector_type(4), aligned(4)));
typedef unsigned short us4 __attribute__((ext_vector_type(4)));   // 8 B

__device__ __forceinline__ float bf2f(u16 v) {
    return __uint_as_float(((unsigned int)v) << 16);
}
__device__ __forceinline__ u16 f2bf(float f) {
    unsigned int u = __float_as_uint(f);
    u = u + 0x7FFFu + ((u >> 16) & 1u);
    return (u16)(u >> 16);
}
__device__ __forceinline__ f32x4 mfma16(s16x8 a, s16x8 b, f32x4 c) {
    return __builtin_amdgcn_mfma_f32_16x16x32_bf16(a, b, c, 0, 0, 0);
}
#define ZERO4 f32x4{0.f, 0.f, 0.f, 0.f}

// ============ prepack: f32 weights -> bf16 MFMA B-fragment layouts ============
__global__ void prepack_kernel(const float* __restrict__ conv_w, const float* __restrict__ Wk,
                               const float* __restrict__ Wv, const float* __restrict__ Wq,
                               const float* __restrict__ W1, const float* __restrict__ W2,
                               u16* __restrict__ Bp, u16* __restrict__ WkvP, u16* __restrict__ WqP,
                               u16* __restrict__ W1T, u16* __restrict__ W2T)
{
    int idx = blockIdx.x * 256 + threadIdx.x;
    if (idx < 294912) {                       // 256 n * 1152 groups
        int n = idx / 1152, g = idx - n * 1152;
        int ic = g / 9, r = g - ic * 9;
        const float* s = conv_w + n * 3456 + ic * 27 + r * 3;
        u16* d = Bp + n * 4608 + g * 4;
        d[0] = f2bf(s[0]); d[1] = f2bf(s[1]); d[2] = f2bf(s[2]); d[3] = 0;
    } else if (idx < 425984) {                // WkvP 512*256
        int i = idx - 294912;
        int n = i >> 8, c = i & 255;
        WkvP[i] = f2bf((n < 256) ? Wk[c * 256 + n] : Wv[c * 256 + (n - 256)]);
    } else if (idx < 491520) {                // WqP 256*256
        int i = idx - 425984;
        int n = i >> 8, c = i & 255;
        WqP[i] = f2bf(Wq[c * 256 + n]);
    } else if (idx < 622592) {                // W1T 512*256
        int i = idx - 491520;
        int h = i >> 8, c = i & 255;
        W1T[i] = f2bf(W1[c * 512 + h]);
    } else if (idx < 753664) {                // W2T 256*512
        int i = idx - 622592;
        int dd = i >> 9, h = i & 511;
        W2T[i] = f2bf(W2[h * 256 + dd]);
    }
}

// ============ fused conv3d(s2)+bias+ReLU+LN_in + k/v GEMM ============
// grid 1024 = b(8) * ox(16) * oyb(8); block 256 (4 waves); M-tile 32 tokens
// slab [16 icl][3 ixl][5 iyl][36 iz]; 4 blocks/CU for latency hiding
__global__ __launch_bounds__(256, 4) void conv_fused(
    const float* __restrict__ x, const u16* __restrict__ Bp, const float* __restrict__ conv_b,
    const float* __restrict__ ln_g, const float* __restrict__ ln_b, const u16* __restrict__ WkvP,
    u16* __restrict__ kbuf, u16* __restrict__ vT)
{
    __shared__ __align__(16) char smem[18560];
    u16* slab   = (u16*)smem;                 // 8640 u16 = 17280 B
    u16* tokbf  = (u16*)smem;                 // alias: [32 m][264 c] = 16896 B
    float* lnred  = (float*)(smem + 17280);   // [4 w][32 m][2] = 1024
    float* lnstat = (float*)(smem + 18304);   // [32 m][2] = 256

    int blk = blockIdx.x;
    int b = blk >> 7, ox = (blk >> 3) & 15, oyb = blk & 7;
    int tid = threadIdx.x, wid = tid >> 6, lane = tid & 63;
    int quad = lane >> 4, l15 = lane & 15;
    int nbase = wid * 64;

    f32x4 acc[2][4];
    #pragma unroll
    for (int i = 0; i < 2; ++i)
        #pragma unroll
        for (int j = 0; j < 4; ++j) acc[i][j] = ZERO4;

    for (int icc = 0; icc < 8; ++icc) {
        __syncthreads();
        // ---- staging: 240 rows x 9 float4-slots = 2160 slots, 9/thread ----
        {
            f32x4u tv[9];
            int so9[9];
            #pragma unroll
            for (int u = 0; u < 9; ++u) {
                int s = tid + u * 256;
                tv[u] = f32x4u{0.f, 0.f, 0.f, 0.f};
                so9[u] = -1;
                if (s < 2160) {
                    int row = (s * 7282) >> 16;           // s/9
                    int c = s - row * 9;
                    int icl = (row * 4369) >> 16;         // row/15
                    int rr = row - icl * 15;
                    int ixl = (rr * 13108) >> 16;         // rr/5
                    int iyl = rr - ixl * 5;
                    const float* xr = x + ((size_t)((b * 128 + icc * 16 + icl) * 33)
                                           + (2 * ox + ixl)) * 1089 + (4 * oyb + iyl) * 33;
                    if (c < 8) tv[u] = *(const f32x4u*)(xr + c * 4);
                    else       tv[u].x = xr[32];          // iz 32; 33..35 stay 0
                    so9[u] = row * 36 + c * 4;
                }
            }
            #pragma unroll
            for (int u = 0; u < 9; ++u) {
                if (so9[u] >= 0) {
                    us4 w;
                    w.x = f2bf(tv[u].x); w.y = f2bf(tv[u].y);
                    w.z = f2bf(tv[u].z); w.w = f2bf(tv[u].w);
                    *(us4*)(slab + so9[u]) = w;
                }
            }
        }
        __syncthreads();
        #pragma unroll 2
        for (int c8 = 0; c8 < 18; ++c8) {
            int k0 = icc * 576 + c8 * 32;
            s16x8 bfr[4];
            #pragma unroll
            for (int fn = 0; fn < 4; ++fn)
                bfr[fn] = *reinterpret_cast<const s16x8*>(
                    Bp + (nbase + fn * 16 + l15) * 4608 + k0 + quad * 8);
            int base0, base1;
            {
                int g = c8 * 8 + quad * 2;
                int icl = g / 9, r9 = g - icl * 9, kx = r9 / 3, ky = r9 - kx * 3;
                base0 = (icl * 15 + kx * 5 + ky) * 36 + 2 * l15;
                g += 1;
                icl = g / 9; r9 = g - icl * 9; kx = r9 / 3; ky = r9 - kx * 3;
                base1 = (icl * 15 + kx * 5 + ky) * 36 + 2 * l15;
            }
            #pragma unroll
            for (int fm = 0; fm < 2; ++fm) {
                union { s16x8 v; ushort2 h[4]; } af;
                const u16* sp0 = slab + base0 + fm * 72;
                const u16* sp1 = slab + base1 + fm * 72;
                af.h[0] = *(const ushort2*)(sp0);
                af.h[1] = *(const ushort2*)(sp0 + 2);
                af.h[2] = *(const ushort2*)(sp1);
                af.h[3] = *(const ushort2*)(sp1 + 2);
                #pragma unroll
                for (int fn = 0; fn < 4; ++fn)
                    acc[fm][fn] = mfma16(af.v, bfr[fn], acc[fm][fn]);
            }
        }
    }
    // ---- bias + relu ----
    #pragma unroll
    for (int fn = 0; fn < 4; ++fn) {
        float bias = conv_b[nbase + fn * 16 + l15];
        #pragma unroll
        for (int fm = 0; fm < 2; ++fm)
            #pragma unroll
            for (int r = 0; r < 4; ++r)
                acc[fm][fn][r] = fmaxf(acc[fm][fn][r] + bias, 0.f);
    }
    // ---- LN_in ----
    #pragma unroll
    for (int fm = 0; fm < 2; ++fm) {
        #pragma unroll
        for (int r = 0; r < 4; ++r) {
            float s = acc[fm][0][r] + acc[fm][1][r] + acc[fm][2][r] + acc[fm][3][r];
            float q2 = acc[fm][0][r] * acc[fm][0][r] + acc[fm][1][r] * acc[fm][1][r]
                     + acc[fm][2][r] * acc[fm][2][r] + acc[fm][3][r] * acc[fm][3][r];
            #pragma unroll
            for (int msk = 1; msk <= 8; msk <<= 1) {
                s  += __shfl_xor(s, msk, 64);
                q2 += __shfl_xor(q2, msk, 64);
            }
            if (l15 == 0) {
                int mm = fm * 16 + quad * 4 + r;
                lnred[(wid * 32 + mm) * 2 + 0] = s;
                lnred[(wid * 32 + mm) * 2 + 1] = q2;
            }
        }
    }
    __syncthreads();
    if (tid < 32) {
        float s = 0, q2 = 0;
        #pragma unroll
        for (int w = 0; w < 4; ++w) { s += lnred[(w * 32 + tid) * 2]; q2 += lnred[(w * 32 + tid) * 2 + 1]; }
        float mu = s * (1.f / 256.f);
        float var = fmaxf(q2 * (1.f / 256.f) - mu * mu, 0.f);
        lnstat[tid * 2]     = mu;
        lnstat[tid * 2 + 1] = rsqrtf(var + 1e-5f);
    }
    __syncthreads();
    {
        float gam[4], bet[4];
        #pragma unroll
        for (int fn = 0; fn < 4; ++fn) {
            int n = nbase + fn * 16 + l15;
            gam[fn] = ln_g[n]; bet[fn] = ln_b[n];
        }
        #pragma unroll
        for (int fm = 0; fm < 2; ++fm)
            #pragma unroll
            for (int r = 0; r < 4; ++r) {
                int mm = fm * 16 + quad * 4 + r;
                float mu = lnstat[mm * 2], rs = lnstat[mm * 2 + 1];
                #pragma unroll
                for (int fn = 0; fn < 4; ++fn) {
                    int n = nbase + fn * 16 + l15;
                    tokbf[mm * 264 + n] = f2bf((acc[fm][fn][r] - mu) * rs * gam[fn] + bet[fn]);
                }
            }
    }
    __syncthreads();
    // ---- k/v GEMM: [32 m]x[512 n], K=256 ----
    f32x4 kacc[2][8];
    #pragma unroll
    for (int i = 0; i < 2; ++i)
        #pragma unroll
        for (int j = 0; j < 8; ++j) kacc[i][j] = ZERO4;
    int n2 = wid * 128;
    #pragma unroll 1
    for (int kc = 0; kc < 8; ++kc) {
        s16x8 a2[2];
        #pragma unroll
        for (int fm = 0; fm < 2; ++fm)
            a2[fm] = *reinterpret_cast<const s16x8*>(tokbf + (fm * 16 + l15) * 264 + kc * 32 + quad * 8);
        #pragma unroll
        for (int fn = 0; fn < 8; ++fn) {
            s16x8 bv = *reinterpret_cast<const s16x8*>(WkvP + (n2 + fn * 16 + l15) * 256 + kc * 32 + quad * 8);
            #pragma unroll
            for (int fm = 0; fm < 2; ++fm)
                kacc[fm][fn] = mfma16(a2[fm], bv, kacc[fm][fn]);
        }
    }
    #pragma unroll
    for (int fm = 0; fm < 2; ++fm)
        #pragma unroll
        for (int r = 0; r < 4; ++r) {
            int mm = fm * 16 + quad * 4 + r;
            int l = (ox * 16 + oyb * 2 + (mm >> 4)) * 16 + (mm & 15);
            #pragma unroll
            for (int fn = 0; fn < 8; ++fn) {
                int n = n2 + fn * 16 + l15;
                u16 v = f2bf(kacc[fm][fn][r]);
                if (n < 256) kbuf[((b << 12) + l) * 256 + n] = v;           // k[b][l][d]
                else         vT[((b * 256 + (n - 256)) << 12) + l] = v;     // vT[b][d][l]
            }
        }
}

// ============ kQ: init tpl, zero colsum/delta, LN_t + q (iter 0) ============
__global__ __launch_bounds__(256) void kQ(
    const float* __restrict__ tinit, float* __restrict__ tpl,
    const float* __restrict__ ln_t_g, const float* __restrict__ ln_t_b,
    const u16* __restrict__ WqP, u16* __restrict__ qbuf,
    float* __restrict__ colsum, float* __restrict__ delta)
{
    __shared__ __align__(16) u16 mls[64 * 264];
    __shared__ float pls[64][4][2];
    __shared__ float stat[64][2];
    int b = blockIdx.x, tid = threadIdx.x;
    int m = tid >> 2, part = tid & 3;
    const float* tp = tinit + m * 256 + part * 64;
    float* tg = tpl + (b * 64 + m) * 256 + part * 64;
    float s = 0, q2 = 0;
    for (int i = 0; i < 64; ++i) {
        float v = tp[i];
        tg[i] = v;
        s += v; q2 += v * v;
    }
    pls[m][part][0] = s; pls[m][part][1] = q2;
    __syncthreads();
    if (tid < 64) {
        float ss = 0, qq = 0;
        #pragma unroll
        for (int p = 0; p < 4; ++p) { ss += pls[tid][p][0]; qq += pls[tid][p][1]; }
        float mu = ss * (1.f / 256.f);
        float var = fmaxf(qq * (1.f / 256.f) - mu * mu, 0.f);
        stat[tid][0] = mu; stat[tid][1] = rsqrtf(var + 1e-5f);
    }
    __syncthreads();
    {
        float mu = stat[m][0], rs = stat[m][1];
        for (int i = 0; i < 64; ++i) {
            int d = part * 64 + i;
            mls[m * 264 + d] = f2bf((tp[i] - mu) * rs * ln_t_g[d] + ln_t_b[d]);
        }
    }
    __syncthreads();
    int wid = tid >> 6, lane = tid & 63, quad = lane >> 4, l15 = lane & 15;
    f32x4 qa[4][4];
    #pragma unroll
    for (int i = 0; i < 4; ++i)
        #pragma unroll
        for (int j = 0; j < 4; ++j) qa[i][j] = ZERO4;
    #pragma unroll 1
    for (int kc = 0; kc < 8; ++kc) {
        s16x8 a[4];
        #pragma unroll
        for (int fm = 0; fm < 4; ++fm)
            a[fm] = *reinterpret_cast<const s16x8*>(mls + (fm * 16 + l15) * 264 + kc * 32 + quad * 8);
        #pragma unroll
        for (int fn = 0; fn < 4; ++fn) {
            s16x8 bv = *reinterpret_cast<const s16x8*>(WqP + (wid * 64 + fn * 16 + l15) * 256 + kc * 32 + quad * 8);
            #pragma unroll
            for (int fm = 0; fm < 4; ++fm)
                qa[fm][fn] = mfma16(a[fm], bv, qa[fm][fn]);
        }
    }
    #pragma unroll
    for (int fm = 0; fm < 4; ++fm)
        #pragma unroll
        for (int fn = 0; fn < 4; ++fn)
            #pragma unroll
            for (int r = 0; r < 4; ++r) {
                int mt = fm * 16 + quad * 4 + r;
                int d = wid * 64 + fn * 16 + l15;
                qbuf[(b * 64 + mt) * 256 + d] = f2bf(qa[fm][fn][r] * 0.0625f);
            }
    if (tid < 64) colsum[b * 64 + tid] = 0.f;
    f32x4* dz = (f32x4*)(delta + b * 16384);
    for (int i = tid; i < 4096; i += 256) dz[i] = ZERO4;
}

// ============ kP: logits + softmax(N) + colsum + PV into delta (atomics) ============
// grid 128 = b(8) * ltg(16); block 256; 256 l rows per block
__global__ __launch_bounds__(256) void kP(
    const u16* __restrict__ qbuf, const u16* __restrict__ kbuf, const u16* __restrict__ vT,
    float* __restrict__ colsum, float* __restrict__ delta, int last, u16* __restrict__ attnT)
{
    __shared__ __align__(16) u16 atile[64 * 264];     // [n][l_local] bf16
    int b = blockIdx.x >> 4, ltg = blockIdx.x & 15;
    int tid = threadIdx.x, wid = tid >> 6, lane = tid & 63;
    int quad = lane >> 4, l15 = lane & 15;
    const u16* qb = qbuf + b * 16384;
    float colp[4] = {0.f, 0.f, 0.f, 0.f};
    #pragma unroll 1
    for (int rt = 0; rt < 4; ++rt) {
        int lrow = ltg * 256 + wid * 64 + rt * 16;
        const u16* arow = kbuf + ((b << 12) + lrow + l15) * 256;
        f32x4 sa[4];
        #pragma unroll
        for (int fn = 0; fn < 4; ++fn) sa[fn] = ZERO4;
        #pragma unroll 1
        for (int kc = 0; kc < 8; ++kc) {
            s16x8 a = *reinterpret_cast<const s16x8*>(arow + kc * 32 + quad * 8);
            #pragma unroll
            for (int fn = 0; fn < 4; ++fn) {
                s16x8 bv = *reinterpret_cast<const s16x8*>(qb + (fn * 16 + l15) * 256 + kc * 32 + quad * 8);
                sa[fn] = mfma16(a, bv, sa[fn]);
            }
        }
        #pragma unroll
        for (int r = 0; r < 4; ++r) {
            float mx = fmaxf(fmaxf(sa[0][r], sa[1][r]), fmaxf(sa[2][r], sa[3][r]));
            #pragma unroll
            for (int msk = 1; msk <= 8; msk <<= 1) mx = fmaxf(mx, __shfl_xor(mx, msk, 64));
            float e[4], sum = 0;
            #pragma unroll
            for (int fn = 0; fn < 4; ++fn) { e[fn] = __expf(sa[fn][r] - mx); sum += e[fn]; }
            #pragma unroll
            for (int msk = 1; msk <= 8; msk <<= 1) sum += __shfl_xor(sum, msk, 64);
            float inv = 1.f / sum;
            #pragma unroll
            for (int fn = 0; fn < 4; ++fn) {
                float p = e[fn] * inv + 1e-8f;
                colp[fn] += p;
                atile[(fn * 16 + l15) * 264 + wid * 64 + rt * 16 + quad * 4 + r] = f2bf(p);
            }
        }
    }
    #pragma unroll
    for (int fn = 0; fn < 4; ++fn) {
        float c = colp[fn];
        c += __shfl_xor(c, 16, 64);
        c += __shfl_xor(c, 32, 64);
        colp[fn] = c;
    }
    if (lane < 16) {
        #pragma unroll
        for (int fn = 0; fn < 4; ++fn)
            atomicAdd(&colsum[b * 64 + fn * 16 + lane], colp[fn]);
    }
    __syncthreads();
    // ---- PV: delta[n][d] += atile[n][l] * vT[d][l], K=256 ----
    f32x4 acc[4][4];
    #pragma unroll
    for (int i = 0; i < 4; ++i)
        #pragma unroll
        for (int j = 0; j < 4; ++j) acc[i][j] = ZERO4;
    #pragma unroll 1
    for (int kc = 0; kc < 8; ++kc) {
        s16x8 a[4];
        #pragma unroll
        for (int fm = 0; fm < 4; ++fm)
            a[fm] = *reinterpret_cast<const s16x8*>(atile + (fm * 16 + l15) * 264 + kc * 32 + quad * 8);
        #pragma unroll
        for (int fn = 0; fn < 4; ++fn) {
            s16x8 bv = *reinterpret_cast<const s16x8*>(
                vT + ((b * 256 + wid * 64 + fn * 16 + l15) << 12) + ltg * 256 + kc * 32 + quad * 8);
            #pragma unroll
            for (int fm = 0; fm < 4; ++fm)
                acc[fm][fn] = mfma16(a[fm], bv, acc[fm][fn]);
        }
    }
    #pragma unroll
    for (int fm = 0; fm < 4; ++fm)
        #pragma unroll
        for (int fn = 0; fn < 4; ++fn)
            #pragma unroll
            for (int r = 0; r < 4; ++r) {
                int nt = fm * 16 + quad * 4 + r;
                int d = wid * 64 + fn * 16 + l15;
                atomicAdd(&delta[(b * 64 + nt) * 256 + d], acc[fm][fn][r]);
            }
    if (last) {
        int n = tid >> 2, lo = (tid & 3) * 64;
        const u16* src = atile + n * 264 + lo;
        u16* dst = attnT + ((b * 64 + n) << 12) + ltg * 256 + lo;
        #pragma unroll
        for (int j = 0; j < 8; ++j)
            *(int4*)(dst + j * 8) = *(const int4*)(src + j * 8);
    }
}

// ============ kT: tpl += delta/colsum; LN_m; MLP; tpl += mlp; LN_t + q (next) ============
// grid 32 = b(8) * mg(4); 16 templates per block
__global__ __launch_bounds__(256) void kT(
    float* __restrict__ tpl, const float* __restrict__ delta, float* __restrict__ colsum,
    const float* __restrict__ ln_m_g, const float* __restrict__ ln_m_b,
    const u16* __restrict__ W1T, const float* __restrict__ b1,
    const u16* __restrict__ W2T, const float* __restrict__ b2,
    const float* __restrict__ ln_t_g, const float* __restrict__ ln_t_b,
    const u16* __restrict__ WqP, u16* __restrict__ qbuf,
    float* __restrict__ deltaz, int last, float* __restrict__ out0)
{
    __shared__ __align__(16) u16 mls[16 * 264];      // 8448
    __shared__ __align__(16) u16 hid[16 * 520];      // 16640
    __shared__ float pls[16][16][2];                 // 2048
    __shared__ float stat[16][2];
    __shared__ float lnr2[4][16][2];
    int b = blockIdx.x >> 2, mg = blockIdx.x & 3;
    int m0 = mg * 16;
    int tid = threadIdx.x, wid = tid >> 6, lane = tid & 63;
    int quad = lane >> 4, l15 = lane & 15;
    // ---- phase 1: v = tpl + delta/colsum; LN_m -> mls; tpl = v ----
    {
        int ml = tid >> 4, part = tid & 15;
        float cinv = 1.f / colsum[b * 64 + m0 + ml];
        float* tg = tpl + (b * 64 + m0 + ml) * 256 + part * 16;
        const float* dg = delta + (b * 64 + m0 + ml) * 256 + part * 16;
        float vbuf[16];
        float s = 0, q2 = 0;
        #pragma unroll
        for (int i = 0; i < 16; ++i) {
            float v = tg[i] + dg[i] * cinv;
            vbuf[i] = v; s += v; q2 += v * v;
        }
        pls[ml][part][0] = s; pls[ml][part][1] = q2;
        __syncthreads();
        if (tid < 16) {
            float ss = 0, qq = 0;
            #pragma unroll
            for (int p = 0; p < 16; ++p) { ss += pls[tid][p][0]; qq += pls[tid][p][1]; }
            float mu = ss * (1.f / 256.f);
            float var = fmaxf(qq * (1.f / 256.f) - mu * mu, 0.f);
            stat[tid][0] = mu; stat[tid][1] = rsqrtf(var + 1e-5f);
        }
        __syncthreads();
        float mu = stat[ml][0], rs = stat[ml][1];
        #pragma unroll
        for (int i = 0; i < 16; ++i) {
            int d = part * 16 + i;
            tg[i] = vbuf[i];
            mls[ml * 264 + d] = f2bf((vbuf[i] - mu) * rs * ln_m_g[d] + ln_m_b[d]);
        }
    }
    __syncthreads();
    // ---- G1: hid = gelu(mls @ W1 + b1); wave -> 128 nh slice ----
    {
        f32x4 ha[8];
        #pragma unroll
        for (int j = 0; j < 8; ++j) ha[j] = ZERO4;
        #pragma unroll 1
        for (int kc = 0; kc < 8; ++kc) {
            s16x8 a = *reinterpret_cast<const s16x8*>(mls + l15 * 264 + kc * 32 + quad * 8);
            #pragma unroll
            for (int fn = 0; fn < 8; ++fn) {
                s16x8 bv = *reinterpret_cast<const s16x8*>(W1T + (wid * 128 + fn * 16 + l15) * 256 + kc * 32 + quad * 8);
                ha[fn] = mfma16(a, bv, ha[fn]);
            }
        }
        #pragma unroll
        for (int fn = 0; fn < 8; ++fn) {
            int nh = wid * 128 + fn * 16 + l15;
            float bb = b1[nh];
            #pragma unroll
            for (int r = 0; r < 4; ++r) {
                float v = ha[fn][r] + bb;
                v = 0.5f * v * (1.f + erff(v * 0.70710678118654752f));
                hid[(quad * 4 + r) * 520 + nh] = f2bf(v);
            }
        }
    }
    __syncthreads();
    // ---- G2: new = tpl + hid @ W2 + b2; LN_t -> mls; out0 on last ----
    {
        f32x4 oa[4];
        #pragma unroll
        for (int j = 0; j < 4; ++j) oa[j] = ZERO4;
        #pragma unroll 1
        for (int kc = 0; kc < 16; ++kc) {
            s16x8 a = *reinterpret_cast<const s16x8*>(hid + l15 * 520 + kc * 32 + quad * 8);
            #pragma unroll
            for (int fn = 0; fn < 4; ++fn) {
                s16x8 bv = *reinterpret_cast<const s16x8*>(W2T + (wid * 64 + fn * 16 + l15) * 512 + kc * 32 + quad * 8);
                oa[fn] = mfma16(a, bv, oa[fn]);
            }
        }
        #pragma unroll
        for (int fn = 0; fn < 4; ++fn) {
            int d = wid * 64 + fn * 16 + l15;
            float bb = b2[d];
            #pragma unroll
            for (int r = 0; r < 4; ++r) {
                int mm = quad * 4 + r;
                oa[fn][r] += bb + tpl[(b * 64 + m0 + mm) * 256 + d];
            }
        }
        // LN_t stats over the 16 new template rows
        #pragma unroll
        for (int r = 0; r < 4; ++r) {
            float s = oa[0][r] + oa[1][r] + oa[2][r] + oa[3][r];
            float q2 = oa[0][r] * oa[0][r] + oa[1][r] * oa[1][r]
                     + oa[2][r] * oa[2][r] + oa[3][r] * oa[3][r];
            #pragma unroll
            for (int msk = 1; msk <= 8; msk <<= 1) {
                s  += __shfl_xor(s, msk, 64);
                q2 += __shfl_xor(q2, msk, 64);
            }
            if (l15 == 0) {
                lnr2[wid][quad * 4 + r][0] = s;
                lnr2[wid][quad * 4 + r][1] = q2;
            }
        }
        __syncthreads();
        if (tid < 16) {
            float ss = 0, qq = 0;
            #pragma unroll
            for (int w = 0; w < 4; ++w) { ss += lnr2[w][tid][0]; qq += lnr2[w][tid][1]; }
            float mu = ss * (1.f / 256.f);
            float var = fmaxf(qq * (1.f / 256.f) - mu * mu, 0.f);
            stat[tid][0] = mu; stat[tid][1] = rsqrtf(var + 1e-5f);
        }
        __syncthreads();
        #pragma unroll
        for (int fn = 0; fn < 4; ++fn) {
            int d = wid * 64 + fn * 16 + l15;
            float gg = last ? 0.f : ln_t_g[d];
            float bt = last ? 0.f : ln_t_b[d];
            #pragma unroll
            for (int r = 0; r < 4; ++r) {
                int mm = quad * 4 + r;
                float v = oa[fn][r];
                tpl[(b * 64 + m0 + mm) * 256 + d] = v;
                if (last) {
                    out0[(b * 256 + d) * 64 + m0 + mm] = v;
                } else {
                    mls[mm * 264 + d] = f2bf((v - stat[mm][0]) * stat[mm][1] * gg + bt);
                }
            }
        }
    }
    if (!last) {
        __syncthreads();
        // ---- q-GEMM for next iteration ----
        f32x4 qa[4];
        #pragma unroll
        for (int j = 0; j < 4; ++j) qa[j] = ZERO4;
        #pragma unroll 1
        for (int kc = 0; kc < 8; ++kc) {
            s16x8 a = *reinterpret_cast<const s16x8*>(mls + l15 * 264 + kc * 32 + quad * 8);
            #pragma unroll
            for (int fn = 0; fn < 4; ++fn) {
                s16x8 bv = *reinterpret_cast<const s16x8*>(WqP + (wid * 64 + fn * 16 + l15) * 256 + kc * 32 + quad * 8);
                qa[fn] = mfma16(a, bv, qa[fn]);
            }
        }
        #pragma unroll
        for (int fn = 0; fn < 4; ++fn)
            #pragma unroll
            for (int r = 0; r < 4; ++r) {
                int mt = m0 + quad * 4 + r;
                int d = wid * 64 + fn * 16 + l15;
                qbuf[(b * 64 + mt) * 256 + d] = f2bf(qa[fn][r] * 0.0625f);
            }
        if (tid < 16) colsum[b * 64 + m0 + tid] = 0.f;
        f32x4* dz = (f32x4*)(deltaz + (b * 64 + m0) * 256);
        for (int i = tid; i < 1024; i += 256) dz[i] = ZERO4;
    }
}

// ============ kE: attn_out = attnT / colsum ============
__global__ void kE(const u16* __restrict__ attnT, const float* __restrict__ colsum,
                   float* __restrict__ out1)
{
    int idx = blockIdx.x * 256 + threadIdx.x;   // < 524288 (x4 elements)
    int e = idx * 4;
    int b = e >> 18, n = (e >> 12) & 63;
    float ci = 1.f / colsum[b * 64 + n];
    const u16* s = attnT + e;
    f32x4 o;
    o.x = bf2f(s[0]) * ci; o.y = bf2f(s[1]) * ci;
    o.z = bf2f(s[2]) * ci; o.w = bf2f(s[3]) * ci;
    *(f32x4*)(out1 + e) = o;
}

// ============ launch ============
extern "C" void kernel_launch(void* const* d_in, const int* in_sizes, int n_in,
                              void* d_out, int out_size, void* d_ws, size_t ws_size,
                              hipStream_t stream)
{
    const float* x       = (const float*)d_in[0];
    const float* tinit   = (const float*)d_in[1];
    const float* conv_w  = (const float*)d_in[2];
    const float* conv_b  = (const float*)d_in[3];
    const float* Wq      = (const float*)d_in[4];
    const float* Wk      = (const float*)d_in[5];
    const float* Wv      = (const float*)d_in[6];
    const float* ln_in_g = (const float*)d_in[7];
    const float* ln_in_b = (const float*)d_in[8];
    const float* ln_t_g  = (const float*)d_in[9];
    const float* ln_t_b  = (const float*)d_in[10];
    const float* ln_m_g  = (const float*)d_in[11];
    const float* ln_m_b  = (const float*)d_in[12];
    const float* W1      = (const float*)d_in[13];
    const float* b1      = (const float*)d_in[14];
    const float* W2      = (const float*)d_in[15];
    const float* b2      = (const float*)d_in[16];

    char* ws = (char*)d_ws;
    u16* Bp       = (u16*)(ws + 0);          // 2,359,296
    u16* WkvP     = (u16*)(ws + 2359296);    //   262,144
    u16* WqP      = (u16*)(ws + 2621440);    //   131,072
    u16* W1T      = (u16*)(ws + 2752512);    //   262,144
    u16* W2T      = (u16*)(ws + 3014656);    //   262,144
    u16* kbuf     = (u16*)(ws + 3276800);    // 16,777,216
    u16* vT       = (u16*)(ws + 20054016);   // 16,777,216
    u16* qbuf     = (u16*)(ws + 36831232);   //   262,144
    u16* attnT    = (u16*)(ws + 37093376);   // 4,194,304
    float* colsum = (float*)(ws + 41287680); //     2,048
    float* tpl    = (float*)(ws + 41289728); //   524,288
    float* delta  = (float*)(ws + 41814016); //   524,288   (total ~42.3 MB)

    float* out0 = (float*)d_out;      // templates_out (8,256,64)
    float* out1 = out0 + 131072;      // attn_out (8,64,16,16,16)

    prepack_kernel<<<2944, 256, 0, stream>>>(conv_w, Wk, Wv, Wq, W1, W2, Bp, WkvP, WqP, W1T, W2T);
    conv_fused<<<1024, 256, 0, stream>>>(x, Bp, conv_b, ln_in_g, ln_in_b, WkvP, kbuf, vT);
    kQ<<<8, 256, 0, stream>>>(tinit, tpl, ln_t_g, ln_t_b, WqP, qbuf, colsum, delta);
    for (int it = 0; it < 6; ++it) {
        int last = (it == 5) ? 1 : 0;
        kP<<<128, 256, 0, stream>>>(qbuf, kbuf, vT, colsum, delta, last, attnT);
        kT<<<32, 256, 0, stream>>>(tpl, delta, colsum, ln_m_g, ln_m_b, W1T, b1, W2T, b2,
                                   ln_t_g, ln_t_b, WqP, qbuf, delta, last, out0);
    }
    kE<<<2048, 256, 0, stream>>>(attnT, colsum, out1);
}